// Round 1
// baseline (289.608 us; speedup 1.0000x reference)
//
#include <hip/hip_runtime.h>
#include <float.h>
#include <math.h>

#define NSAMPLE 8192
#define KSEL 9          // K+1: keep 9 smallest incl. self
#define KNN 8
#define BLK 256
#define EPS_F 1e-12f

// ---------------------------------------------------------------------------
// Kernel 1: gather sampled means/sh0 into float4 arrays in workspace.
// ---------------------------------------------------------------------------
__global__ __launch_bounds__(BLK) void gather_k(
    const float* __restrict__ means, const float* __restrict__ sh0,
    const int* __restrict__ idx,
    float4* __restrict__ sm4, float4* __restrict__ ss4)
{
    int i = blockIdx.x * BLK + threadIdx.x;
    if (i >= NSAMPLE) return;
    int id = idx[i];
    const float* m = means + 3 * (long long)id;
    const float* s = sh0 + 3 * (long long)id;
    sm4[i] = make_float4(m[0], m[1], m[2], 0.0f);
    ss4[i] = make_float4(s[0], s[1], s[2], 0.0f);
}

// ---------------------------------------------------------------------------
// Kernel 2: one block per row. Find 9 smallest d2 (incl. self=0), drop the
// smallest, accumulate sum_k exp(-dist_k) * ||ss_i - ss_k||^2 into rowsum.
// ---------------------------------------------------------------------------
__global__ __launch_bounds__(BLK) void knn_k(
    const float4* __restrict__ sm4, const float4* __restrict__ ss4,
    float* __restrict__ rowsum)
{
    const int row  = blockIdx.x;
    const int t    = threadIdx.x;
    const int wave = t >> 6;
    const int lane = t & 63;

    __shared__ float w_d2[BLK / 64];
    __shared__ int   w_tid[BLK / 64];
    __shared__ int   w_gix[BLK / 64];
    __shared__ float res_d2[KSEL];
    __shared__ int   res_ix[KSEL];
    __shared__ int   s_winner;

    float4 p = sm4[row];  // broadcast, L1-hit

    // per-thread sorted top-9 (ascending d2)
    float bd[KSEL];
    int   bi[KSEL];
#pragma unroll
    for (int k = 0; k < KSEL; ++k) { bd[k] = FLT_MAX; bi[k] = -1; }

    for (int j = t; j < NSAMPLE; j += BLK) {
        float4 q = sm4[j];
        float dx = p.x - q.x, dy = p.y - q.y, dz = p.z - q.z;
        float d2 = fmaf(dx, dx, fmaf(dy, dy, dz * dz));
        if (d2 < bd[KSEL - 1]) {
            int k = KSEL - 1;
            while (k > 0 && bd[k - 1] > d2) {
                bd[k] = bd[k - 1]; bi[k] = bi[k - 1]; --k;
            }
            bd[k] = d2; bi[k] = j;
        }
    }

    // Block-level 9-way selection: merge 256 sorted lists by repeated min of
    // per-thread heads. 9 passes.
    int head = 0;
    for (int pass = 0; pass < KSEL; ++pass) {
        float cd = (head < KSEL) ? bd[head] : FLT_MAX;
        int   cg = (head < KSEL) ? bi[head] : -1;
        int   ct = t;
        // wave shuffle-min (carry global idx + thread id)
        for (int off = 32; off > 0; off >>= 1) {
            float od = __shfl_down(cd, off);
            int   og = __shfl_down(cg, off);
            int   ot = __shfl_down(ct, off);
            if (od < cd) { cd = od; cg = og; ct = ot; }
        }
        if (lane == 0) { w_d2[wave] = cd; w_tid[wave] = ct; w_gix[wave] = cg; }
        __syncthreads();
        if (t == 0) {
            float md = w_d2[0]; int mt = w_tid[0]; int mg = w_gix[0];
            for (int w = 1; w < BLK / 64; ++w) {
                if (w_d2[w] < md) { md = w_d2[w]; mt = w_tid[w]; mg = w_gix[w]; }
            }
            res_d2[pass] = md; res_ix[pass] = mg; s_winner = mt;
        }
        __syncthreads();
        if (t == s_winner) ++head;
        // s_winner is next written by t0 only after the next pass's first
        // __syncthreads, so no extra barrier needed here.
    }

    // res[0] is the dropped self/zero-distance entry; res[1..8] are the 8 NN.
    float4 si = ss4[row];
    float val = 0.0f;
    if (t < KNN) {
        int j = res_ix[t + 1];
        float4 sj = ss4[j];
        float d = sqrtf(fmaxf(res_d2[t + 1], EPS_F));
        float w = expf(-d);
        float ax = si.x - sj.x, ay = si.y - sj.y, az = si.z - sj.z;
        val = w * (ax * ax + ay * ay + az * az);
    }
    if (wave == 0) {
        val += __shfl_down(val, 4);
        val += __shfl_down(val, 2);
        val += __shfl_down(val, 1);
        if (t == 0) rowsum[row] = val;
    }
}

// ---------------------------------------------------------------------------
// Kernel 3: reduce 8192 row sums -> scalar mean.
// ---------------------------------------------------------------------------
__global__ __launch_bounds__(BLK) void reduce_k(
    const float* __restrict__ rowsum, float* __restrict__ out)
{
    __shared__ float sbuf[BLK / 64];
    int t = threadIdx.x;
    float v = 0.0f;
    for (int i = t; i < NSAMPLE; i += BLK) v += rowsum[i];
    for (int off = 32; off > 0; off >>= 1) v += __shfl_down(v, off);
    if ((t & 63) == 0) sbuf[t >> 6] = v;
    __syncthreads();
    if (t == 0) {
        float s = 0.0f;
        for (int w = 0; w < BLK / 64; ++w) s += sbuf[w];
        out[0] = s * (1.0f / (float)(NSAMPLE * KNN * 3));
    }
}

// ---------------------------------------------------------------------------
extern "C" void kernel_launch(void* const* d_in, const int* in_sizes, int n_in,
                              void* d_out, int out_size, void* d_ws, size_t ws_size,
                              hipStream_t stream)
{
    const float* means = (const float*)d_in[0];
    const float* sh0   = (const float*)d_in[1];
    const int*   idx   = (const int*)d_in[2];

    float4* sm4    = (float4*)d_ws;
    float4* ss4    = sm4 + NSAMPLE;
    float*  rowsum = (float*)(ss4 + NSAMPLE);

    gather_k<<<NSAMPLE / BLK, BLK, 0, stream>>>(means, sh0, idx, sm4, ss4);
    knn_k<<<NSAMPLE, BLK, 0, stream>>>(sm4, ss4, rowsum);
    reduce_k<<<1, BLK, 0, stream>>>(rowsum, (float*)d_out);
}

// Round 2
// 179.037 us; speedup vs baseline: 1.6176x; 1.6176x over previous
//
#include <hip/hip_runtime.h>
#include <float.h>
#include <math.h>

#define NSAMPLE 8192
#define KSEL 9          // K+1: keep 9 smallest incl. self
#define KNN 8
#define BLK 256
#define EPS_F 1e-12f

#define CHUNKS 16
#define CHUNK (NSAMPLE / CHUNKS)     // 512 candidates per chunk
#define ROWBLKS (NSAMPLE / BLK)      // 32 row-blocks
#define IDX_BITS 13
#define IDX_MASK 0x1FFFu             // low 13 bits = candidate index
#define VAL_MASK 0xFFFFE000u         // high 19 bits = d2 (sign+exp+10 mantissa)

// ---------------------------------------------------------------------------
// Kernel 1: gather sampled means/sh0 into float4 arrays in workspace.
// ---------------------------------------------------------------------------
__global__ __launch_bounds__(BLK) void gather_k(
    const float* __restrict__ means, const float* __restrict__ sh0,
    const int* __restrict__ idx,
    float4* __restrict__ sm4, float4* __restrict__ ss4)
{
    int i = blockIdx.x * BLK + threadIdx.x;
    if (i >= NSAMPLE) return;
    int id = idx[i];
    const float* m = means + 3 * (long long)id;
    const float* s = sh0 + 3 * (long long)id;
    sm4[i] = make_float4(m[0], m[1], m[2], 0.0f);
    ss4[i] = make_float4(s[0], s[1], s[2], 0.0f);
}

// ---------------------------------------------------------------------------
// Kernel 2: partial KNN. Grid = CHUNKS x ROWBLKS blocks. Each thread owns one
// row, scans one 512-candidate LDS tile, keeps top-9 smallest packed
// (d2 | idx) u32 in a descending-sorted register array. No cross-thread
// merge; partials written to ws for kernel 3.
// Packed compare: d2 >= 0 so float bits compare as uint; low 13 idx bits only
// break ties within 2^-10 relative d2 (exact d2 recomputed in merge).
// ---------------------------------------------------------------------------
__global__ __launch_bounds__(BLK) void knn_part_k(
    const float4* __restrict__ sm4, unsigned int* __restrict__ partial)
{
    const int t = threadIdx.x;
    const int rowblk = blockIdx.x & (ROWBLKS - 1);
    const int c = blockIdx.x / ROWBLKS;
    const int row = rowblk * BLK + t;
    const int cbase = c * CHUNK;

    __shared__ float4 cand[CHUNK];   // 8 KB
    for (int i = t; i < CHUNK; i += BLK) cand[i] = sm4[cbase + i];
    __syncthreads();

    float4 p = sm4[row];

    unsigned int s[KSEL];            // s[0] = worst (largest), s[8] = best
#pragma unroll
    for (int k = 0; k < KSEL; ++k) s[k] = 0xFFFFFFFFu;

#pragma unroll 4
    for (int j = 0; j < CHUNK; ++j) {
        float4 q = cand[j];          // wave-broadcast LDS read
        float dx = p.x - q.x, dy = p.y - q.y, dz = p.z - q.z;
        float d2 = fmaf(dx, dx, fmaf(dy, dy, dz * dz));
        unsigned int pv = (__float_as_uint(d2) & VAL_MASK) |
                          (unsigned int)(cbase + j);
        if (pv < s[0]) {
            s[0] = pv;               // replace worst, then one bubble pass
#pragma unroll
            for (int k = 0; k < KSEL - 1; ++k) {
                unsigned int a = s[k], b = s[k + 1];
                s[k] = a > b ? a : b;
                s[k + 1] = a > b ? b : a;
            }
        }
    }

#pragma unroll
    for (int k = 0; k < KSEL; ++k)
        partial[(c * KSEL + k) * NSAMPLE + row] = s[k];
}

// ---------------------------------------------------------------------------
// Kernel 3: merge 16x9 partials per row, drop the closest (self / zero-dup),
// recompute exact d2 for the 8 neighbors, accumulate loss terms.
// ---------------------------------------------------------------------------
__global__ __launch_bounds__(BLK) void knn_merge_k(
    const unsigned int* __restrict__ partial,
    const float4* __restrict__ sm4, const float4* __restrict__ ss4,
    float* __restrict__ rowsum)
{
    const int r = blockIdx.x * BLK + threadIdx.x;

    unsigned int s[KSEL];
#pragma unroll
    for (int k = 0; k < KSEL; ++k) s[k] = 0xFFFFFFFFu;

    for (int e = 0; e < CHUNKS * KSEL; ++e) {
        unsigned int pv = partial[e * NSAMPLE + r];   // coalesced per wave
        if (pv < s[0]) {
            s[0] = pv;
#pragma unroll
            for (int k = 0; k < KSEL - 1; ++k) {
                unsigned int a = s[k], b = s[k + 1];
                s[k] = a > b ? a : b;
                s[k + 1] = a > b ? b : a;
            }
        }
    }

    // s[8] is the global min (self or an identical-coordinate duplicate whose
    // diff is 0 either way) -> dropped. s[0..7] are the 8 neighbors.
    float4 pm = sm4[r];
    float4 ps = ss4[r];
    float acc = 0.0f;
#pragma unroll
    for (int k = 0; k < KNN; ++k) {
        int j = (int)(s[k] & IDX_MASK);
        float4 qm = sm4[j];
        float dx = pm.x - qm.x, dy = pm.y - qm.y, dz = pm.z - qm.z;
        float d2 = fmaf(dx, dx, fmaf(dy, dy, dz * dz));
        float d = sqrtf(fmaxf(d2, EPS_F));
        float w = expf(-d);
        float4 qs = ss4[j];
        float ax = ps.x - qs.x, ay = ps.y - qs.y, az = ps.z - qs.z;
        acc += w * (ax * ax + ay * ay + az * az);
    }
    rowsum[r] = acc;
}

// ---------------------------------------------------------------------------
// Kernel 4: reduce 8192 row sums -> scalar mean.
// ---------------------------------------------------------------------------
__global__ __launch_bounds__(BLK) void reduce_k(
    const float* __restrict__ rowsum, float* __restrict__ out)
{
    __shared__ float sbuf[BLK / 64];
    int t = threadIdx.x;
    float v = 0.0f;
    for (int i = t; i < NSAMPLE; i += BLK) v += rowsum[i];
    for (int off = 32; off > 0; off >>= 1) v += __shfl_down(v, off);
    if ((t & 63) == 0) sbuf[t >> 6] = v;
    __syncthreads();
    if (t == 0) {
        float s = 0.0f;
        for (int w = 0; w < BLK / 64; ++w) s += sbuf[w];
        out[0] = s * (1.0f / (float)(NSAMPLE * KNN * 3));
    }
}

// ---------------------------------------------------------------------------
extern "C" void kernel_launch(void* const* d_in, const int* in_sizes, int n_in,
                              void* d_out, int out_size, void* d_ws, size_t ws_size,
                              hipStream_t stream)
{
    const float* means = (const float*)d_in[0];
    const float* sh0   = (const float*)d_in[1];
    const int*   idx   = (const int*)d_in[2];

    char* ws = (char*)d_ws;
    float4* sm4    = (float4*)ws;                          // 128 KB
    float4* ss4    = (float4*)(ws + NSAMPLE * 16);         // 128 KB
    float*  rowsum = (float*)(ws + 2 * NSAMPLE * 16);      // 32 KB
    unsigned int* partial = (unsigned int*)(ws + 2 * NSAMPLE * 16 + NSAMPLE * 4);
    // partial: CHUNKS*KSEL*NSAMPLE*4 = 4.5 MB

    gather_k<<<NSAMPLE / BLK, BLK, 0, stream>>>(means, sh0, idx, sm4, ss4);
    knn_part_k<<<CHUNKS * ROWBLKS, BLK, 0, stream>>>(sm4, partial);
    knn_merge_k<<<NSAMPLE / BLK, BLK, 0, stream>>>(partial, sm4, ss4, rowsum);
    reduce_k<<<1, BLK, 0, stream>>>(rowsum, (float*)d_out);
}

// Round 3
// 135.622 us; speedup vs baseline: 2.1354x; 1.3201x over previous
//
#include <hip/hip_runtime.h>
#include <float.h>
#include <math.h>

#define NSAMPLE 8192
#define KSEL 9          // K+1: keep 9 smallest incl. self
#define KNN 8
#define BLK 256
#define EPS_F 1e-12f

#define CHUNKS 32
#define CHUNK (NSAMPLE / CHUNKS)     // 256 candidates per chunk
#define ROWBLKS (NSAMPLE / BLK)      // 32 row-blocks
#define NPART (CHUNKS * KSEL)        // 288 partial entries per row
#define IDX_MASK 0x1FFFu             // low 13 bits = candidate index
#define VAL_MASK 0xFFFFE000u         // high 19 bits = d2 (sign+exp+10 mantissa)
#define SCALE (1.0f / (float)(NSAMPLE * KNN * 3))

__device__ __forceinline__ unsigned umn(unsigned a, unsigned b) { return a < b ? a : b; }
__device__ __forceinline__ unsigned umx(unsigned a, unsigned b) { return a > b ? a : b; }

// Branchless insert of x into descending-sorted s[0..8] (s[0]=worst, s[8]=best).
// new s[k] = clamp(x, [s[k+1], s[k]]) == med3; ascending k only reads
// not-yet-overwritten s[k+1]. 17 min/max, no branch.
__device__ __forceinline__ void insert9(unsigned s[KSEL], unsigned x)
{
#pragma unroll
    for (int k = 0; k < KSEL - 1; ++k)
        s[k] = umx(s[k + 1], umn(x, s[k]));
    s[KSEL - 1] = umn(x, s[KSEL - 1]);
}

// ---------------------------------------------------------------------------
// Kernel 1: gather sampled means/sh0; w component of sm4 = |mean|^2.
// Thread 0 also zero-inits d_out for the merge kernel's atomics.
// ---------------------------------------------------------------------------
__global__ __launch_bounds__(BLK) void gather_k(
    const float* __restrict__ means, const float* __restrict__ sh0,
    const int* __restrict__ idx,
    float4* __restrict__ sm4, float4* __restrict__ ss4,
    float* __restrict__ out)
{
    int i = blockIdx.x * BLK + threadIdx.x;
    if (i == 0) out[0] = 0.0f;
    if (i >= NSAMPLE) return;
    int id = idx[i];
    const float* m = means + 3 * (long long)id;
    const float* s = sh0 + 3 * (long long)id;
    float mx = m[0], my = m[1], mz = m[2];
    sm4[i] = make_float4(mx, my, mz, fmaf(mx, mx, fmaf(my, my, mz * mz)));
    ss4[i] = make_float4(s[0], s[1], s[2], 0.0f);
}

// ---------------------------------------------------------------------------
// Kernel 2: partial KNN. Grid = CHUNKS x ROWBLKS. Thread owns one row, scans
// a 256-candidate LDS tile with branchless top-9 of packed (d2|idx).
// d2 in sq-form (matches reference), clamped at 0 so self packs minimal.
// ---------------------------------------------------------------------------
__global__ __launch_bounds__(BLK) void knn_part_k(
    const float4* __restrict__ sm4, unsigned int* __restrict__ partial)
{
    const int t = threadIdx.x;
    const int rowblk = blockIdx.x & (ROWBLKS - 1);
    const int c = blockIdx.x / ROWBLKS;
    const int row = rowblk * BLK + t;
    const int cbase = c * CHUNK;

    __shared__ float4 cand[CHUNK];   // 4 KB
    cand[t] = sm4[cbase + t];        // CHUNK == BLK

    float4 p = sm4[row];
    float n2x = -2.0f * p.x, n2y = -2.0f * p.y, n2z = -2.0f * p.z;
    float sp = p.w;
    __syncthreads();

    unsigned s[KSEL];
#pragma unroll
    for (int k = 0; k < KSEL; ++k) s[k] = 0xFFFFFFFFu;

#pragma unroll 8
    for (int j = 0; j < CHUNK; ++j) {
        float4 q = cand[j];          // wave-broadcast LDS read
        float d2 = fmaf(n2x, q.x, fmaf(n2y, q.y, fmaf(n2z, q.z, sp + q.w)));
        d2 = fmaxf(d2, 0.0f);        // cancellation guard: self must pack minimal
        unsigned x = (__float_as_uint(d2) & VAL_MASK) | (unsigned)(cbase + j);
        insert9(s, x);
    }

#pragma unroll
    for (int k = 0; k < KSEL; ++k)
        partial[(c * KSEL + k) * NSAMPLE + row] = s[k];   // coalesced
}

// ---------------------------------------------------------------------------
// Kernel 3: merge 32x9 partials per row, drop global min (self / zero-dup),
// compute loss terms, wave-reduce, atomicAdd into d_out.
// ---------------------------------------------------------------------------
__global__ __launch_bounds__(BLK) void knn_merge_k(
    const unsigned int* __restrict__ partial,
    const float4* __restrict__ sm4, const float4* __restrict__ ss4,
    float* __restrict__ out)
{
    const int r = blockIdx.x * BLK + threadIdx.x;

    unsigned s[KSEL];
#pragma unroll
    for (int k = 0; k < KSEL; ++k) s[k] = 0xFFFFFFFFu;

#pragma unroll 8
    for (int e = 0; e < NPART; ++e)
        insert9(s, partial[e * NSAMPLE + r]);   // coalesced per wave

    // s[8] = global min (self, or an identical-coordinate dup whose term is 0
    // either way) -> dropped. s[0..7] are the 8 neighbors.
    float4 pm = sm4[r];
    float4 ps = ss4[r];
    float acc = 0.0f;
#pragma unroll
    for (int k = 0; k < KNN; ++k) {
        int j = (int)(s[k] & IDX_MASK);
        float4 qm = sm4[j];
        float dx = pm.x - qm.x, dy = pm.y - qm.y, dz = pm.z - qm.z;
        float d2 = fmaf(dx, dx, fmaf(dy, dy, dz * dz));
        float d = sqrtf(fmaxf(d2, EPS_F));
        float w = expf(-d);
        float4 qs = ss4[j];
        float ax = ps.x - qs.x, ay = ps.y - qs.y, az = ps.z - qs.z;
        acc += w * (ax * ax + ay * ay + az * az);
    }
    acc *= SCALE;

    // wave-64 reduce, one atomic per wave
    for (int off = 32; off > 0; off >>= 1) acc += __shfl_down(acc, off);
    if ((threadIdx.x & 63) == 0) atomicAdd(out, acc);
}

// ---------------------------------------------------------------------------
extern "C" void kernel_launch(void* const* d_in, const int* in_sizes, int n_in,
                              void* d_out, int out_size, void* d_ws, size_t ws_size,
                              hipStream_t stream)
{
    const float* means = (const float*)d_in[0];
    const float* sh0   = (const float*)d_in[1];
    const int*   idx   = (const int*)d_in[2];

    char* ws = (char*)d_ws;
    float4* sm4 = (float4*)ws;                             // 128 KB
    float4* ss4 = (float4*)(ws + NSAMPLE * 16);            // 128 KB
    unsigned int* partial = (unsigned int*)(ws + 2 * NSAMPLE * 16);
    // partial: NPART*NSAMPLE*4 = 9.4 MB

    gather_k<<<NSAMPLE / BLK, BLK, 0, stream>>>(means, sh0, idx, sm4, ss4,
                                                (float*)d_out);
    knn_part_k<<<CHUNKS * ROWBLKS, BLK, 0, stream>>>(sm4, partial);
    knn_merge_k<<<NSAMPLE / BLK, BLK, 0, stream>>>(partial, sm4, ss4,
                                                   (float*)d_out);
}